// Round 1
// baseline (850.809 us; speedup 1.0000x reference)
//
#include <hip/hip_runtime.h>
#include <math.h>

#define NUM_LAYERS 10
#define DD 3

__device__ __forceinline__ float det3(const float* __restrict__ W) {
    // row-major 3x3
    return W[0] * (W[4] * W[8] - W[5] * W[7])
         - W[1] * (W[3] * W[8] - W[5] * W[6])
         + W[2] * (W[3] * W[7] - W[4] * W[6]);
}

__global__ __launch_bounds__(256) void flow_kernel(
    const float* __restrict__ x,
    const float* __restrict__ affine,   // (N, 60)
    const float* __restrict__ Ws,       // (10, 3, 3)
    const float* __restrict__ bs,       // (10, 3)
    const float* __restrict__ lastW,    // (3, 3)
    const float* __restrict__ lastb,    // (3,)
    float* __restrict__ out_z,          // (N, 3)
    float* __restrict__ out_ld,         // (N,)
    int N)
{
    const int row = blockIdx.x * blockDim.x + threadIdx.x;
    if (row >= N) return;

    // ---- constant log|det| sum (uniform across all threads; scalar regs) ----
    float const_ld = 0.0f;
#pragma unroll
    for (int i = 0; i < NUM_LAYERS; ++i) {
        const_ld += logf(fabsf(det3(Ws + i * 9)));
    }
    const_ld += logf(fabsf(det3(lastW)));

    // ---- load this row's data ----
    const float LOG2PI = 1.8378770664093453f;
    const float AFFINE_EPS = 1e-4f;

    float z0 = x[(size_t)row * 3 + 0];
    float z1 = x[(size_t)row * 3 + 1];
    float z2 = x[(size_t)row * 3 + 2];

    // 60 floats of affine info, vectorized as 15 float4 (row*240B is 16B-aligned)
    float4 av[15];
    const float4* ap = reinterpret_cast<const float4*>(affine + (size_t)row * 60);
#pragma unroll
    for (int i = 0; i < 15; ++i) av[i] = ap[i];
    const float* af = reinterpret_cast<const float*>(av);

    float ld = 0.0f;

#pragma unroll
    for (int i = 0; i < NUM_LAYERS; ++i) {
        const float* W = Ws + i * 9;
        const float* b = bs + i * 3;
        // z = z @ W + b   (out[j] = sum_k z[k] * W[k*3+j] + b[j])
        float n0 = fmaf(z0, W[0], fmaf(z1, W[3], fmaf(z2, W[6], b[0])));
        float n1 = fmaf(z0, W[1], fmaf(z1, W[4], fmaf(z2, W[7], b[1])));
        float n2 = fmaf(z0, W[2], fmaf(z1, W[5], fmaf(z2, W[8], b[2])));

        const float s0 = af[i * 6 + 0];
        const float s1 = af[i * 6 + 1];
        const float s2 = af[i * 6 + 2];
        const float t0 = af[i * 6 + 3];
        const float t1 = af[i * 6 + 4];
        const float t2 = af[i * 6 + 5];

        const float sc0 = 1.0f / (1.0f + expf(-(s0 + 2.0f))) + AFFINE_EPS;
        const float sc1 = 1.0f / (1.0f + expf(-(s1 + 2.0f))) + AFFINE_EPS;
        const float sc2 = 1.0f / (1.0f + expf(-(s2 + 2.0f))) + AFFINE_EPS;

        z0 = fmaf(n0, sc0, t0);
        z1 = fmaf(n1, sc1, t1);
        z2 = fmaf(n2, sc2, t2);

        ld += logf(sc0) + logf(sc1) + logf(sc2);
    }

    // final linear layer
    {
        const float* W = lastW;
        float n0 = fmaf(z0, W[0], fmaf(z1, W[3], fmaf(z2, W[6], lastb[0])));
        float n1 = fmaf(z0, W[1], fmaf(z1, W[4], fmaf(z2, W[7], lastb[1])));
        float n2 = fmaf(z0, W[2], fmaf(z1, W[5], fmaf(z2, W[8], lastb[2])));
        z0 = n0; z1 = n1; z2 = n2;
    }

    ld += const_ld;
    ld += -0.5f * (z0 * z0 + LOG2PI)
        + -0.5f * (z1 * z1 + LOG2PI)
        + -0.5f * (z2 * z2 + LOG2PI);

    out_z[(size_t)row * 3 + 0] = z0;
    out_z[(size_t)row * 3 + 1] = z1;
    out_z[(size_t)row * 3 + 2] = z2;
    out_ld[row] = ld;
}

extern "C" void kernel_launch(void* const* d_in, const int* in_sizes, int n_in,
                              void* d_out, int out_size, void* d_ws, size_t ws_size,
                              hipStream_t stream) {
    const float* x      = (const float*)d_in[0];
    const float* affine = (const float*)d_in[1];
    const float* Ws     = (const float*)d_in[2];
    const float* bs     = (const float*)d_in[3];
    const float* lastW  = (const float*)d_in[4];
    const float* lastb  = (const float*)d_in[5];

    const int N = in_sizes[0] / 3;

    float* out_z  = (float*)d_out;
    float* out_ld = (float*)d_out + (size_t)N * 3;

    const int block = 256;
    const int grid = (N + block - 1) / block;
    flow_kernel<<<grid, block, 0, stream>>>(x, affine, Ws, bs, lastW, lastb,
                                            out_z, out_ld, N);
}

// Round 2
// 677.828 us; speedup vs baseline: 1.2552x; 1.2552x over previous
//
#include <hip/hip_runtime.h>
#include <math.h>

#define NUM_LAYERS 10

// LDS layout: 64 rows x 60 floats, row stride padded to 61.
// Read pattern: lane t reads lds_af[61*t + c] -> bank (29*t + c) % 32,
// gcd(29,32)=1 -> 2 lanes/bank across wave64 = conflict-free (m136).
#define AF_PAD 61

__device__ __forceinline__ float det3(const float* __restrict__ W) {
    return W[0] * (W[4] * W[8] - W[5] * W[7])
         - W[1] * (W[3] * W[8] - W[5] * W[6])
         + W[2] * (W[3] * W[7] - W[4] * W[6]);
}

__global__ __launch_bounds__(64) void flow_kernel(
    const float* __restrict__ x,
    const float* __restrict__ affine,   // (N, 60)
    const float* __restrict__ Ws,       // (10, 3, 3)
    const float* __restrict__ bs,       // (10, 3)
    const float* __restrict__ lastW,    // (3, 3)
    const float* __restrict__ lastb,    // (3,)
    float* __restrict__ out_z,          // (N, 3)
    float* __restrict__ out_ld,         // (N,)
    int N)
{
    __shared__ float lds_af[64 * AF_PAD];   // 15616 B -> 10 blocks/CU

    const int tid = threadIdx.x;
    const int row0 = blockIdx.x * 64;

    // ---- coalesced staging: this block's 64 rows = 960 contiguous float4 ----
    // Lane t loads float4 #(k*64+t): each wave-instruction covers 1 KB
    // contiguous, fully consumed -> no L2 retention needed.
    const float4* ap = reinterpret_cast<const float4*>(affine) + (size_t)blockIdx.x * 960;
    float4 v[15];
#pragma unroll
    for (int k = 0; k < 15; ++k) v[k] = ap[k * 64 + tid];
#pragma unroll
    for (int k = 0; k < 15; ++k) {
        const int idx = k * 64 + tid;       // float4 index within block region
        const int r   = idx / 15;           // local row
        const int e4  = idx - r * 15;       // float4 slot within row
        float* p = &lds_af[r * AF_PAD + e4 * 4];
        p[0] = v[k].x; p[1] = v[k].y; p[2] = v[k].z; p[3] = v[k].w;
    }
    __syncthreads();

    const int row = row0 + tid;
    if (row >= N) return;   // N = 2^21 is divisible by 64; guard for safety

    // ---- constant log|det| sum (uniform across threads; scalar-cached) ----
    float const_ld = 0.0f;
#pragma unroll
    for (int i = 0; i < NUM_LAYERS; ++i) {
        const_ld += logf(fabsf(det3(Ws + i * 9)));
    }
    const_ld += logf(fabsf(det3(lastW)));

    const float LOG2PI = 1.8378770664093453f;
    const float AFFINE_EPS = 1e-4f;

    float z0 = x[(size_t)row * 3 + 0];
    float z1 = x[(size_t)row * 3 + 1];
    float z2 = x[(size_t)row * 3 + 2];

    const float* af = &lds_af[tid * AF_PAD];
    float ld = 0.0f;

#pragma unroll
    for (int i = 0; i < NUM_LAYERS; ++i) {
        const float* W = Ws + i * 9;
        const float* b = bs + i * 3;
        // z = z @ W + b   (out[j] = sum_k z[k] * W[k*3+j] + b[j])
        float n0 = fmaf(z0, W[0], fmaf(z1, W[3], fmaf(z2, W[6], b[0])));
        float n1 = fmaf(z0, W[1], fmaf(z1, W[4], fmaf(z2, W[7], b[1])));
        float n2 = fmaf(z0, W[2], fmaf(z1, W[5], fmaf(z2, W[8], b[2])));

        const float s0 = af[i * 6 + 0];
        const float s1 = af[i * 6 + 1];
        const float s2 = af[i * 6 + 2];
        const float t0 = af[i * 6 + 3];
        const float t1 = af[i * 6 + 4];
        const float t2 = af[i * 6 + 5];

        const float sc0 = 1.0f / (1.0f + expf(-(s0 + 2.0f))) + AFFINE_EPS;
        const float sc1 = 1.0f / (1.0f + expf(-(s1 + 2.0f))) + AFFINE_EPS;
        const float sc2 = 1.0f / (1.0f + expf(-(s2 + 2.0f))) + AFFINE_EPS;

        z0 = fmaf(n0, sc0, t0);
        z1 = fmaf(n1, sc1, t1);
        z2 = fmaf(n2, sc2, t2);

        ld += logf(sc0) + logf(sc1) + logf(sc2);
    }

    // final linear layer
    {
        const float* W = lastW;
        float n0 = fmaf(z0, W[0], fmaf(z1, W[3], fmaf(z2, W[6], lastb[0])));
        float n1 = fmaf(z0, W[1], fmaf(z1, W[4], fmaf(z2, W[7], lastb[1])));
        float n2 = fmaf(z0, W[2], fmaf(z1, W[5], fmaf(z2, W[8], lastb[2])));
        z0 = n0; z1 = n1; z2 = n2;
    }

    ld += const_ld;
    ld += -0.5f * (z0 * z0 + LOG2PI)
        + -0.5f * (z1 * z1 + LOG2PI)
        + -0.5f * (z2 * z2 + LOG2PI);

    out_z[(size_t)row * 3 + 0] = z0;
    out_z[(size_t)row * 3 + 1] = z1;
    out_z[(size_t)row * 3 + 2] = z2;
    out_ld[row] = ld;
}

extern "C" void kernel_launch(void* const* d_in, const int* in_sizes, int n_in,
                              void* d_out, int out_size, void* d_ws, size_t ws_size,
                              hipStream_t stream) {
    const float* x      = (const float*)d_in[0];
    const float* affine = (const float*)d_in[1];
    const float* Ws     = (const float*)d_in[2];
    const float* bs     = (const float*)d_in[3];
    const float* lastW  = (const float*)d_in[4];
    const float* lastb  = (const float*)d_in[5];

    const int N = in_sizes[0] / 3;

    float* out_z  = (float*)d_out;
    float* out_ld = (float*)d_out + (size_t)N * 3;

    const int block = 64;
    const int grid = (N + block - 1) / block;
    flow_kernel<<<grid, block, 0, stream>>>(x, affine, Ws, bs, lastW, lastb,
                                            out_z, out_ld, N);
}